// Round 5
// baseline (8264.816 us; speedup 1.0000x reference)
//
#include <hip/hip_runtime.h>

#define B_ 8
#define C_ 256
#define H_ 64
#define W_ 64
#define HW_ 4096
#define A_ 9
#define SITES 36864      // A_*HW_
#define NPOST 1000
#define XCLIPF 4.1351666f   // (float)4.135166556742356
#define IMGF 1024.0f

__device__ inline unsigned keyf(float v) {
  unsigned u = __float_as_uint(v);
  return (u & 0x80000000u) ? ~u : (u | 0x80000000u);  // ascending uint == ascending float
}

// ---------------- K1: 3x3 conv + bias + relu, bit-exact f32, LDS-tiled ----------------
// Exact order preserved: per pixel, 9 independent fmaf chains over ci (ascending),
// then acc = ((((p0+p1)+p2)+...)+p8) + bias.  Zero-padded halo taps are exact no-ops.
// grid: B_*C_*2 blocks; block: 256 threads, 8 px each (32 rows x 64 cols half-image)
#define NCI 4
__global__ __launch_bounds__(256) void conv3_tiled(
    const float* __restrict__ x, const float* __restrict__ w,
    const float* __restrict__ bias, float* __restrict__ feats) {
#pragma clang fp contract(off)
  int b   = blockIdx.x >> 9;
  int co  = (blockIdx.x >> 1) & 255;
  int half = blockIdx.x & 1;
  int r_base = half << 5;                       // 0 or 32
  int tr = threadIdx.x >> 3;                    // 0..31 (row within half)
  int c0 = (threadIdx.x & 7) << 3;              // 0,8,...,56

  __shared__ float xs[NCI][34][66];
  __shared__ float ws[2304];
  for (int i = threadIdx.x; i < 2304; i += 256) ws[i] = w[(size_t)co * 2304 + i];

  const float* xb = x + (size_t)b * C_ * HW_;
  float part[8][9];
#pragma unroll
  for (int p = 0; p < 8; ++p)
#pragma unroll
    for (int t = 0; t < 9; ++t) part[p][t] = 0.f;

  for (int ci0 = 0; ci0 < C_; ci0 += NCI) {
    __syncthreads();
    for (int i = threadIdx.x; i < NCI * 34 * 66; i += 256) {
      int cit = i / (34 * 66);
      int rem = i - cit * (34 * 66);
      int r = rem / 66, c = rem - r * 66;
      int gr = r_base + r - 1, gc = c - 1;
      float v = 0.f;
      if ((unsigned)gr < 64u && (unsigned)gc < 64u)
        v = xb[(size_t)(ci0 + cit) * HW_ + gr * 64 + gc];
      ((float*)xs)[i] = v;
    }
    __syncthreads();
#pragma unroll
    for (int cit = 0; cit < NCI; ++cit) {
      float w9[9];
#pragma unroll
      for (int t = 0; t < 9; ++t) w9[t] = ws[(ci0 + cit) * 9 + t];
      float xw[3][10];
#pragma unroll
      for (int d = 0; d < 3; ++d)
#pragma unroll
        for (int j = 0; j < 10; ++j) xw[d][j] = xs[cit][tr + d][c0 + j];
#pragma unroll
      for (int t = 0; t < 9; ++t) {
        int kh = t / 3, kw = t - kh * 3;
#pragma unroll
        for (int p = 0; p < 8; ++p)
          part[p][t] = fmaf(w9[t], xw[kh][p + kw], part[p][t]);
      }
    }
  }
  float bv = bias[co];
  float* fo = feats + ((size_t)b * C_ + co) * HW_ + (r_base + tr) * 64 + c0;
#pragma unroll
  for (int p = 0; p < 8; ++p) {
    float a = 0.f;
#pragma unroll
    for (int t = 0; t < 9; ++t) a = a + part[p][t];  // tap-ordered, left-assoc
    a = a + bv;
    fo[p] = a > 0.f ? a : 0.f;
  }
}

// ---------------- K2: 1x1 convs (36 box + 9 obj), bit-exact f32 chain, all batches ----------------
__global__ __launch_bounds__(256) void conv1_f32(
    const float* __restrict__ feats,
    const float* __restrict__ box_w, const float* __restrict__ box_b,
    const float* __restrict__ obj_w, const float* __restrict__ obj_b,
    float* __restrict__ tbox, float* __restrict__ scores) {
#pragma clang fp contract(off)
  int b  = blockIdx.x / 720;
  int rc = blockIdx.x - b * 720;
  int c  = rc >> 4;                              // [0,45)
  int hw = ((rc & 15) << 8) + threadIdx.x;
  const float* wrow = (c < 36) ? (box_w + (size_t)c * C_) : (obj_w + (size_t)(c - 36) * C_);
  const float* f = feats + (size_t)b * C_ * HW_ + hw;
  float acc = 0.f;
  for (int ci = 0; ci < C_; ++ci)
    acc = fmaf(wrow[ci], f[(size_t)ci * HW_], acc);
  if (c < 36) {
    int k = c / 9, a = c - k * 9;
    tbox[(size_t)b * 4 * SITES + (size_t)k * SITES + (size_t)a * HW_ + hw] = acc + box_b[c];
  } else {
    int a = c - 36;
    scores[(size_t)b * SITES + (size_t)a * HW_ + hw] = acc + obj_b[a];
  }
}

// ---------------- K3: exact radix-select of the 1000th-smallest key per batch ----------------
// one block per batch; finds K = key at ascending rank 999, count_less, zeroes cnt
__global__ __launch_bounds__(1024) void radix_select(
    const float* __restrict__ scores, unsigned* __restrict__ Kout,
    int* __restrict__ needEq, int* __restrict__ cnt) {
  int b = blockIdx.x;
  const float* s = scores + (size_t)b * SITES;
  __shared__ unsigned hist[256];
  __shared__ unsigned sh_prefix, sh_mask, sh_cless;
  __shared__ int sh_target;
  if (threadIdx.x == 0) { sh_prefix = 0; sh_mask = 0; sh_target = NPOST - 1; sh_cless = 0; }
  for (int shift = 24; shift >= 0; shift -= 8) {
    if (threadIdx.x < 256) hist[threadIdx.x] = 0;
    __syncthreads();
    unsigned prefix = sh_prefix, mask = sh_mask;
    for (int i = threadIdx.x; i < SITES; i += 1024) {
      unsigned k = keyf(s[i]);
      if ((k & mask) == prefix) atomicAdd(&hist[(k >> shift) & 255u], 1u);
    }
    __syncthreads();
    if (threadIdx.x == 0) {
      unsigned cum = 0; int t = sh_target; int v = 0;
      for (; v < 256; ++v) {
        unsigned h = hist[v];
        if (cum + h > (unsigned)t) break;
        cum += h;
      }
      sh_prefix |= ((unsigned)v) << shift;
      sh_mask   |= 0xFFu << shift;
      sh_target  = t - (int)cum;
      sh_cless  += cum;
    }
    __syncthreads();
  }
  if (threadIdx.x == 0) {
    Kout[b] = sh_prefix;
    needEq[b] = NPOST - (int)sh_cless;   // # of key==K items to take, in ascending site order
    cnt[b] = 0;
  }
}

// ---------------- K4: compact the selected 1000 sites (stable-argsort tie semantics) ----------------
__global__ __launch_bounds__(256) void compact_sel(
    const float* __restrict__ scores, const unsigned* __restrict__ Kout,
    const int* __restrict__ needEq, int* __restrict__ cnt, int* __restrict__ sel) {
  int b = blockIdx.x / 144;
  int i = (blockIdx.x % 144) * 256 + threadIdx.x;
  const float* s = scores + (size_t)b * SITES;
  unsigned K = Kout[b];
  unsigned k = keyf(s[i]);
  if (k > K) return;
  if (k == K) {
    int eq = 0;                               // # equal-key sites with smaller index
    for (int j = 0; j < i; ++j) eq += (keyf(s[j]) == K);
    if (eq >= needEq[b]) return;
  }
  int pos = atomicAdd(&cnt[b], 1);
  sel[b * 1024 + pos] = i;
}

// ---------------- K5: exact descending order of the selected 1000 (tie: site index asc) ----------------
__global__ __launch_bounds__(1024) void order_sel(
    const float* __restrict__ scores, const int* __restrict__ sel,
    int* __restrict__ slot_site, float* __restrict__ s2) {
  int b = blockIdx.x;
  int r = threadIdx.x;
  __shared__ float ss[NPOST];
  __shared__ int st[NPOST];
  if (r < NPOST) {
    int site = sel[b * 1024 + r];
    st[r] = site;
    ss[r] = scores[(size_t)b * SITES + site];
  }
  __syncthreads();
  if (r < NPOST) {
    float sr = ss[r]; int sir = st[r];
    int d = 0;
    for (int q = 0; q < NPOST; ++q) {
      float sq = ss[q];
      d += (int)((sq > sr) || (sq == sr && st[q] < sir));
    }
    slot_site[b * NPOST + d] = sir;
    s2[(size_t)b * NPOST + d] = sr;
  }
}

// ---------------- K6: faithful f32 decode of the 1000 slots (separate mul/add, expf) ----------------
__global__ __launch_bounds__(256) void decode_k(
    const float* __restrict__ tbox, const int* __restrict__ slot_site,
    float* __restrict__ b2) {
#pragma clang fp contract(off)
  int idx = blockIdx.x * 256 + threadIdx.x;
  if (idx >= B_ * NPOST) return;
  int b = idx / NPOST, d = idx - b * NPOST;
  int site = slot_site[(size_t)b * NPOST + d];
  int a = site / HW_;
  int hw = site - a * HW_;
  int h = hw / W_, wc = hw - h * W_;
  int sidx = a / 3, ridx = a - sidx * 3;
  float scale = (sidx == 0) ? 128.f : ((sidx == 1) ? 256.f : 512.f);
  float ratio = (ridx == 0) ? 0.5f : ((ridx == 1) ? 1.0f : 2.0f);
  float sq = sqrtf(ratio);
  float wsa = scale / sq;
  float hsa = scale * sq;
  float cx = ((float)wc + 0.5f) * 16.f;
  float cy = ((float)h + 0.5f) * 16.f;
  float ax1 = cx - wsa * 0.5f;
  float ay1 = cy - hsa * 0.5f;
  float ax2 = cx + wsa * 0.5f;
  float ay2 = cy + hsa * 0.5f;
  float aw = ax2 - ax1, ah = ay2 - ay1;
  float m1 = 0.5f * aw, m2 = 0.5f * ah;
  float acx = ax1 + m1, acy = ay1 + m2;
  const float* tb = tbox + (size_t)b * 4 * SITES + site;
  float t0 = tb[0];
  float t1 = tb[SITES];
  float t2 = tb[2 * (size_t)SITES];
  float t3 = tb[3 * (size_t)SITES];
  if (t2 < -XCLIPF) t2 = -XCLIPF;
  if (t2 > XCLIPF) t2 = XCLIPF;
  if (t3 < -XCLIPF) t3 = -XCLIPF;
  if (t3 > XCLIPF) t3 = XCLIPF;
  float pm0 = t0 * aw;  float pcx = pm0 + acx;
  float pm1 = t1 * ah;  float pcy = pm1 + acy;
  float pw = expf(t2) * aw;
  float ph = expf(t3) * ah;
  float hw0 = 0.5f * pw, hh0 = 0.5f * ph;
  float x1 = pcx - hw0, y1 = pcy - hh0;
  float x2 = pcx + hw0, y2 = pcy + hh0;
  x1 = x1 < 0.f ? 0.f : (x1 > IMGF ? IMGF : x1);
  y1 = y1 < 0.f ? 0.f : (y1 > IMGF ? IMGF : y1);
  x2 = x2 < 0.f ? 0.f : (x2 > IMGF ? IMGF : x2);
  y2 = y2 < 0.f ? 0.f : (y2 > IMGF ? IMGF : y2);
  float* o = b2 + ((size_t)b * NPOST + d) * 4;
  o[0] = x1; o[1] = y1; o[2] = x2; o[3] = y2;
}

// ---------------- K7: literal fori_loop NMS (f32 IoU) + compaction + zero fill ----------------
__global__ __launch_bounds__(1024) void nms_compact(
    const float* __restrict__ b2, const float* __restrict__ s2,
    float* __restrict__ out) {
#pragma clang fp contract(off)
  int b = blockIdx.x;
  int j = threadIdx.x;
  __shared__ float bx[NPOST * 4];
  __shared__ float ar[NPOST];
  __shared__ int keep[NPOST];
  if (j < NPOST) {
    const float* src = b2 + ((size_t)b * NPOST + j) * 4;
    bx[j * 4 + 0] = src[0];
    bx[j * 4 + 1] = src[1];
    bx[j * 4 + 2] = src[2];
    bx[j * 4 + 3] = src[3];
    ar[j] = (src[2] - src[0]) * (src[3] - src[1]);
    keep[j] = 1;
  }
  __syncthreads();
  float jx1 = 0, jy1 = 0, jx2 = 0, jy2 = 0, ja = 0;
  if (j < NPOST) {
    jx1 = bx[j * 4 + 0]; jy1 = bx[j * 4 + 1];
    jx2 = bx[j * 4 + 2]; jy2 = bx[j * 4 + 3];
    ja = ar[j];
  }
  for (int i = 0; i < NPOST; ++i) {
    int ki = keep[i];  // row i never written during iteration i (writes target j>i)
    if (ki && j > i && j < NPOST) {
      float lx = fmaxf(bx[i * 4 + 0], jx1);
      float ly = fmaxf(bx[i * 4 + 1], jy1);
      float rx = fminf(bx[i * 4 + 2], jx2);
      float ry = fminf(bx[i * 4 + 3], jy2);
      float iw = rx - lx; if (iw < 0.f) iw = 0.f;
      float ih = ry - ly; if (ih < 0.f) ih = 0.f;
      float inter = iw * ih;
      float denom = (ar[i] + ja) - inter;
      float iou = inter / denom;
      if (iou > 0.7f) keep[j] = 0;
    }
    __syncthreads();
  }
  if (j < NPOST) {
    int total = 0;
    for (int q = 0; q < NPOST; ++q) total += keep[q];
    int before = 0;
    for (int q = 0; q < j; ++q) before += keep[q];
    if (keep[j]) {
      size_t ob = (size_t)b * (NPOST * 5) + (size_t)before * 5;
      out[ob + 0] = jx1;
      out[ob + 1] = jy1;
      out[ob + 2] = jx2;
      out[ob + 3] = jy2;
      out[ob + 4] = s2[(size_t)b * NPOST + j];
    }
    if (j >= total) {
      size_t ob = (size_t)b * (NPOST * 5) + (size_t)j * 5;
      for (int c = 0; c < 5; ++c) out[ob + c] = 0.f;
    }
  }
}

extern "C" void kernel_launch(void* const* d_in, const int* in_sizes, int n_in,
                              void* d_out, int out_size, void* d_ws, size_t ws_size,
                              hipStream_t stream) {
  const float *x = nullptr, *conv_w = nullptr, *conv_b = nullptr,
              *box_w = nullptr, *box_b = nullptr, *obj_w = nullptr, *obj_b = nullptr;
  for (int i = 0; i < n_in; ++i) {
    switch (in_sizes[i]) {
      case 8388608: x = (const float*)d_in[i]; break;      // 8*256*64*64
      case 589824:  conv_w = (const float*)d_in[i]; break; // 256*256*9
      case 256:     conv_b = (const float*)d_in[i]; break;
      case 9216:    box_w = (const float*)d_in[i]; break;  // 36*256
      case 36:      box_b = (const float*)d_in[i]; break;
      case 2304:    obj_w = (const float*)d_in[i]; break;  // 9*256
      case 9:       obj_b = (const float*)d_in[i]; break;
    }
  }
  float* out = (float*)d_out;

  // Workspace ~39.7 MB (round 0 established >= ~82 MB is safe)
  char* p = (char*)d_ws;
  auto alloc = [&](size_t n) { char* q = p; p += (n + 255) & ~255ull; return (void*)q; };
  float* feats  = (float*)alloc((size_t)B_ * C_ * HW_ * 4);       // 33.55 MB
  float* tbox   = (float*)alloc((size_t)B_ * 4 * SITES * 4);      // 4.72 MB
  float* scores = (float*)alloc((size_t)B_ * SITES * 4);          // 1.18 MB
  unsigned* Kout = (unsigned*)alloc(B_ * 4);
  int* needEq    = (int*)alloc(B_ * 4);
  int* cnt       = (int*)alloc(B_ * 4);
  int* sel       = (int*)alloc((size_t)B_ * 1024 * 4);
  int* slot_site = (int*)alloc((size_t)B_ * NPOST * 4);
  float* s2      = (float*)alloc((size_t)B_ * NPOST * 4);
  float* b2      = (float*)alloc((size_t)B_ * NPOST * 4 * 4);

  hipLaunchKernelGGL(conv3_tiled, dim3(B_ * C_ * 2), dim3(256), 0, stream,
                     x, conv_w, conv_b, feats);
  hipLaunchKernelGGL(conv1_f32, dim3(B_ * 45 * 16), dim3(256), 0, stream,
                     feats, box_w, box_b, obj_w, obj_b, tbox, scores);
  hipLaunchKernelGGL(radix_select, dim3(B_), dim3(1024), 0, stream,
                     scores, Kout, needEq, cnt);
  hipLaunchKernelGGL(compact_sel, dim3(B_ * 144), dim3(256), 0, stream,
                     scores, Kout, needEq, cnt, sel);
  hipLaunchKernelGGL(order_sel, dim3(B_), dim3(1024), 0, stream,
                     scores, sel, slot_site, s2);
  hipLaunchKernelGGL(decode_k, dim3((B_ * NPOST + 255) / 256), dim3(256), 0, stream,
                     tbox, slot_site, b2);
  hipLaunchKernelGGL(nms_compact, dim3(B_), dim3(1024), 0, stream, b2, s2, out);
}

// Round 6
// 2807.851 us; speedup vs baseline: 2.9435x; 2.9435x over previous
//
#include <hip/hip_runtime.h>

#define B_ 8
#define C_ 256
#define H_ 64
#define W_ 64
#define HW_ 4096
#define A_ 9
#define SITES 36864      // A_*HW_
#define NPOST 1000
#define XCLIPF 4.1351666f   // (float)4.135166556742356
#define IMGF 1024.0f

__device__ inline unsigned keyf(float v) {
  unsigned u = __float_as_uint(v);
  return (u & 0x80000000u) ? ~u : (u | 0x80000000u);  // ascending uint == ascending float
}

// ---------------- K1: 3x3 conv + bias + relu, bit-exact f32, LDS-FREE ----------------
// Exact order preserved (identical to the round-4 passing kernel): per pixel, 9
// independent fmaf chains over ci ascending; partials summed kh-major left-assoc;
// zero halo taps are exact no-ops (chain stays +0.0f; x + 0.0f == x).
// grid: B_*C_*2 blocks; 256 threads = 32 rows x 8 chunks; 8 px/thread.
// Row data: 6 dwordx4 global loads/ci (L1/L2-hit); horizontal halo via __shfl(lane±1);
// weights are wave-uniform -> scalar K$ loads. No LDS, no barriers.
__global__ __launch_bounds__(256) void conv3_shfl(
    const float* __restrict__ x, const float* __restrict__ w,
    const float* __restrict__ bias, float* __restrict__ feats) {
#pragma clang fp contract(off)
  int b    = blockIdx.x >> 9;
  int co   = (blockIdx.x >> 1) & 255;
  int half = blockIdx.x & 1;
  int rih  = threadIdx.x >> 3;          // 0..31
  int chunk= threadIdx.x & 7;           // 0..7
  int gr   = (half << 5) + rih;         // global row 0..63
  int c0   = chunk << 3;                // col base 0,8,...,56
  int trow = gr > 0 ? gr - 1 : 0;       // clamped (value zeroed below if OOB)
  int brow = gr < 63 ? gr + 1 : 63;
  bool top0 = (gr == 0), bot0 = (gr == 63);
  bool lef0 = (chunk == 0), rig0 = (chunk == 7);

  const float* xb = x + (size_t)b * C_ * HW_;
  const float4* pT = (const float4*)(xb + (size_t)trow * W_ + c0);
  const float4* pM = (const float4*)(xb + (size_t)gr   * W_ + c0);
  const float4* pB = (const float4*)(xb + (size_t)brow * W_ + c0);
  const float* wp = w + (size_t)co * (C_ * 9);

  float acc[8][9];
#pragma unroll
  for (int p = 0; p < 8; ++p)
#pragma unroll
    for (int t = 0; t < 9; ++t) acc[p][t] = 0.f;

  for (int ci = 0; ci < C_; ++ci) {
    float4 tA = pT[0], tB = pT[1];
    float4 mA = pM[0], mB = pM[1];
    float4 bA = pB[0], bB = pB[1];
    pT += HW_ / 4; pM += HW_ / 4; pB += HW_ / 4;

    float T[10], M[10], Bo[10];
    T[1]=tA.x; T[2]=tA.y; T[3]=tA.z; T[4]=tA.w; T[5]=tB.x; T[6]=tB.y; T[7]=tB.z; T[8]=tB.w;
    M[1]=mA.x; M[2]=mA.y; M[3]=mA.z; M[4]=mA.w; M[5]=mB.x; M[6]=mB.y; M[7]=mB.z; M[8]=mB.w;
    Bo[1]=bA.x; Bo[2]=bA.y; Bo[3]=bA.z; Bo[4]=bA.w; Bo[5]=bB.x; Bo[6]=bB.y; Bo[7]=bB.z; Bo[8]=bB.w;
    if (top0) {
#pragma unroll
      for (int j = 1; j <= 8; ++j) T[j] = 0.f;
    }
    if (bot0) {
#pragma unroll
      for (int j = 1; j <= 8; ++j) Bo[j] = 0.f;
    }
    // horizontal halo from neighbor lanes (zero first so gr==0/63 halos propagate)
    T[0]  = __shfl_up(T[8], 1u);   if (lef0) T[0]  = 0.f;
    T[9]  = __shfl_down(T[1], 1u); if (rig0) T[9]  = 0.f;
    M[0]  = __shfl_up(M[8], 1u);   if (lef0) M[0]  = 0.f;
    M[9]  = __shfl_down(M[1], 1u); if (rig0) M[9]  = 0.f;
    Bo[0] = __shfl_up(Bo[8], 1u);  if (lef0) Bo[0] = 0.f;
    Bo[9] = __shfl_down(Bo[1], 1u);if (rig0) Bo[9] = 0.f;

    float w9[9];
#pragma unroll
    for (int t = 0; t < 9; ++t) w9[t] = wp[ci * 9 + t];   // wave-uniform -> s_load

#pragma unroll
    for (int p = 0; p < 8; ++p) {
      acc[p][0] = fmaf(w9[0], T[p],    acc[p][0]);
      acc[p][1] = fmaf(w9[1], T[p+1],  acc[p][1]);
      acc[p][2] = fmaf(w9[2], T[p+2],  acc[p][2]);
      acc[p][3] = fmaf(w9[3], M[p],    acc[p][3]);
      acc[p][4] = fmaf(w9[4], M[p+1],  acc[p][4]);
      acc[p][5] = fmaf(w9[5], M[p+2],  acc[p][5]);
      acc[p][6] = fmaf(w9[6], Bo[p],   acc[p][6]);
      acc[p][7] = fmaf(w9[7], Bo[p+1], acc[p][7]);
      acc[p][8] = fmaf(w9[8], Bo[p+2], acc[p][8]);
    }
  }

  float bv = bias[co];
  float ov[8];
#pragma unroll
  for (int p = 0; p < 8; ++p) {
    float a = 0.f;
#pragma unroll
    for (int t = 0; t < 9; ++t) a = a + acc[p][t];  // tap-ordered, left-assoc
    a = a + bv;
    ov[p] = a > 0.f ? a : 0.f;
  }
  float4* fo = (float4*)(feats + ((size_t)b * C_ + co) * HW_ + (size_t)gr * W_ + c0);
  fo[0] = make_float4(ov[0], ov[1], ov[2], ov[3]);
  fo[1] = make_float4(ov[4], ov[5], ov[6], ov[7]);
}

// ---------------- K2: fused 1x1 convs (36 box + 9 obj), bit-exact f32 chains ----------------
// one thread per (b,hw); feats read ONCE; each channel's fmaf chain over ci ascending
// is preserved exactly (identical per-channel order to the round-4/5 passing kernel).
__global__ __launch_bounds__(256) void conv1_fused(
    const float* __restrict__ feats,
    const float* __restrict__ box_w, const float* __restrict__ box_b,
    const float* __restrict__ obj_w, const float* __restrict__ obj_b,
    float* __restrict__ tbox, float* __restrict__ scores) {
#pragma clang fp contract(off)
  int idx = blockIdx.x * 256 + threadIdx.x;   // [0, B_*HW_)
  int b = idx >> 12;
  int hw = idx & 4095;
  const float* f = feats + (size_t)b * C_ * HW_ + hw;
  float acc[45];
#pragma unroll
  for (int c = 0; c < 45; ++c) acc[c] = 0.f;
  for (int ci = 0; ci < C_; ++ci) {
    float fv = f[(size_t)ci * HW_];
#pragma unroll
    for (int c = 0; c < 36; ++c)
      acc[c] = fmaf(box_w[c * C_ + ci], fv, acc[c]);       // uniform w -> s_load
#pragma unroll
    for (int a = 0; a < 9; ++a)
      acc[36 + a] = fmaf(obj_w[a * C_ + ci], fv, acc[36 + a]);
  }
#pragma unroll
  for (int c = 0; c < 36; ++c) {
    int k = c / 9, a = c - k * 9;
    tbox[(size_t)b * 4 * SITES + (size_t)k * SITES + (size_t)a * HW_ + hw] = acc[c] + box_b[c];
  }
#pragma unroll
  for (int a = 0; a < 9; ++a)
    scores[(size_t)b * SITES + (size_t)a * HW_ + hw] = acc[36 + a] + obj_b[a];
}

// ---------------- K3: exact radix-select of the 1000th-smallest key per batch ----------------
__global__ __launch_bounds__(1024) void radix_select(
    const float* __restrict__ scores, unsigned* __restrict__ Kout,
    int* __restrict__ needEq, int* __restrict__ cnt) {
  int b = blockIdx.x;
  const float* s = scores + (size_t)b * SITES;
  __shared__ unsigned hist[256];
  __shared__ unsigned sh_prefix, sh_mask, sh_cless;
  __shared__ int sh_target;
  if (threadIdx.x == 0) { sh_prefix = 0; sh_mask = 0; sh_target = NPOST - 1; sh_cless = 0; }
  for (int shift = 24; shift >= 0; shift -= 8) {
    if (threadIdx.x < 256) hist[threadIdx.x] = 0;
    __syncthreads();
    unsigned prefix = sh_prefix, mask = sh_mask;
    for (int i = threadIdx.x; i < SITES; i += 1024) {
      unsigned k = keyf(s[i]);
      if ((k & mask) == prefix) atomicAdd(&hist[(k >> shift) & 255u], 1u);
    }
    __syncthreads();
    if (threadIdx.x == 0) {
      unsigned cum = 0; int t = sh_target; int v = 0;
      for (; v < 256; ++v) {
        unsigned h = hist[v];
        if (cum + h > (unsigned)t) break;
        cum += h;
      }
      sh_prefix |= ((unsigned)v) << shift;
      sh_mask   |= 0xFFu << shift;
      sh_target  = t - (int)cum;
      sh_cless  += cum;
    }
    __syncthreads();
  }
  if (threadIdx.x == 0) {
    Kout[b] = sh_prefix;
    needEq[b] = NPOST - (int)sh_cless;
    cnt[b] = 0;
  }
}

// ---------------- K4: compact the selected 1000 sites (stable-argsort tie semantics) ----------------
__global__ __launch_bounds__(256) void compact_sel(
    const float* __restrict__ scores, const unsigned* __restrict__ Kout,
    const int* __restrict__ needEq, int* __restrict__ cnt, int* __restrict__ sel) {
  int b = blockIdx.x / 144;
  int i = (blockIdx.x % 144) * 256 + threadIdx.x;
  const float* s = scores + (size_t)b * SITES;
  unsigned K = Kout[b];
  unsigned k = keyf(s[i]);
  if (k > K) return;
  if (k == K) {
    int eq = 0;
    for (int j = 0; j < i; ++j) eq += (keyf(s[j]) == K);
    if (eq >= needEq[b]) return;
  }
  int pos = atomicAdd(&cnt[b], 1);
  sel[b * 1024 + pos] = i;
}

// ---------------- K5: exact descending order of the selected 1000 (tie: site index asc) ----------------
__global__ __launch_bounds__(1024) void order_sel(
    const float* __restrict__ scores, const int* __restrict__ sel,
    int* __restrict__ slot_site, float* __restrict__ s2) {
  int b = blockIdx.x;
  int r = threadIdx.x;
  __shared__ float ss[NPOST];
  __shared__ int st[NPOST];
  if (r < NPOST) {
    int site = sel[b * 1024 + r];
    st[r] = site;
    ss[r] = scores[(size_t)b * SITES + site];
  }
  __syncthreads();
  if (r < NPOST) {
    float sr = ss[r]; int sir = st[r];
    int d = 0;
    for (int q = 0; q < NPOST; ++q) {
      float sq = ss[q];
      d += (int)((sq > sr) || (sq == sr && st[q] < sir));
    }
    slot_site[b * NPOST + d] = sir;
    s2[(size_t)b * NPOST + d] = sr;
  }
}

// ---------------- K6: faithful f32 decode of the 1000 slots ----------------
__global__ __launch_bounds__(256) void decode_k(
    const float* __restrict__ tbox, const int* __restrict__ slot_site,
    float* __restrict__ b2) {
#pragma clang fp contract(off)
  int idx = blockIdx.x * 256 + threadIdx.x;
  if (idx >= B_ * NPOST) return;
  int b = idx / NPOST, d = idx - b * NPOST;
  int site = slot_site[(size_t)b * NPOST + d];
  int a = site / HW_;
  int hw = site - a * HW_;
  int h = hw / W_, wc = hw - h * W_;
  int sidx = a / 3, ridx = a - sidx * 3;
  float scale = (sidx == 0) ? 128.f : ((sidx == 1) ? 256.f : 512.f);
  float ratio = (ridx == 0) ? 0.5f : ((ridx == 1) ? 1.0f : 2.0f);
  float sq = sqrtf(ratio);
  float wsa = scale / sq;
  float hsa = scale * sq;
  float cx = ((float)wc + 0.5f) * 16.f;
  float cy = ((float)h + 0.5f) * 16.f;
  float ax1 = cx - wsa * 0.5f;
  float ay1 = cy - hsa * 0.5f;
  float ax2 = cx + wsa * 0.5f;
  float ay2 = cy + hsa * 0.5f;
  float aw = ax2 - ax1, ah = ay2 - ay1;
  float m1 = 0.5f * aw, m2 = 0.5f * ah;
  float acx = ax1 + m1, acy = ay1 + m2;
  const float* tb = tbox + (size_t)b * 4 * SITES + site;
  float t0 = tb[0];
  float t1 = tb[SITES];
  float t2 = tb[2 * (size_t)SITES];
  float t3 = tb[3 * (size_t)SITES];
  if (t2 < -XCLIPF) t2 = -XCLIPF;
  if (t2 > XCLIPF) t2 = XCLIPF;
  if (t3 < -XCLIPF) t3 = -XCLIPF;
  if (t3 > XCLIPF) t3 = XCLIPF;
  float pm0 = t0 * aw;  float pcx = pm0 + acx;
  float pm1 = t1 * ah;  float pcy = pm1 + acy;
  float pw = expf(t2) * aw;
  float ph = expf(t3) * ah;
  float hw0 = 0.5f * pw, hh0 = 0.5f * ph;
  float x1 = pcx - hw0, y1 = pcy - hh0;
  float x2 = pcx + hw0, y2 = pcy + hh0;
  x1 = x1 < 0.f ? 0.f : (x1 > IMGF ? IMGF : x1);
  y1 = y1 < 0.f ? 0.f : (y1 > IMGF ? IMGF : y1);
  x2 = x2 < 0.f ? 0.f : (x2 > IMGF ? IMGF : x2);
  y2 = y2 < 0.f ? 0.f : (y2 > IMGF ? IMGF : y2);
  float* o = b2 + ((size_t)b * NPOST + d) * 4;
  o[0] = x1; o[1] = y1; o[2] = x2; o[3] = y2;
}

// ---------------- K7: literal fori_loop NMS (f32 IoU) + compaction + zero fill ----------------
__global__ __launch_bounds__(1024) void nms_compact(
    const float* __restrict__ b2, const float* __restrict__ s2,
    float* __restrict__ out) {
#pragma clang fp contract(off)
  int b = blockIdx.x;
  int j = threadIdx.x;
  __shared__ float bx[NPOST * 4];
  __shared__ float ar[NPOST];
  __shared__ int keep[NPOST];
  if (j < NPOST) {
    const float* src = b2 + ((size_t)b * NPOST + j) * 4;
    bx[j * 4 + 0] = src[0];
    bx[j * 4 + 1] = src[1];
    bx[j * 4 + 2] = src[2];
    bx[j * 4 + 3] = src[3];
    ar[j] = (src[2] - src[0]) * (src[3] - src[1]);
    keep[j] = 1;
  }
  __syncthreads();
  float jx1 = 0, jy1 = 0, jx2 = 0, jy2 = 0, ja = 0;
  if (j < NPOST) {
    jx1 = bx[j * 4 + 0]; jy1 = bx[j * 4 + 1];
    jx2 = bx[j * 4 + 2]; jy2 = bx[j * 4 + 3];
    ja = ar[j];
  }
  for (int i = 0; i < NPOST; ++i) {
    int ki = keep[i];  // row i never written during iteration i (writes target j>i)
    if (ki && j > i && j < NPOST) {
      float lx = fmaxf(bx[i * 4 + 0], jx1);
      float ly = fmaxf(bx[i * 4 + 1], jy1);
      float rx = fminf(bx[i * 4 + 2], jx2);
      float ry = fminf(bx[i * 4 + 3], jy2);
      float iw = rx - lx; if (iw < 0.f) iw = 0.f;
      float ih = ry - ly; if (ih < 0.f) ih = 0.f;
      float inter = iw * ih;
      float denom = (ar[i] + ja) - inter;
      float iou = inter / denom;
      if (iou > 0.7f) keep[j] = 0;
    }
    __syncthreads();
  }
  if (j < NPOST) {
    int total = 0;
    for (int q = 0; q < NPOST; ++q) total += keep[q];
    int before = 0;
    for (int q = 0; q < j; ++q) before += keep[q];
    if (keep[j]) {
      size_t ob = (size_t)b * (NPOST * 5) + (size_t)before * 5;
      out[ob + 0] = jx1;
      out[ob + 1] = jy1;
      out[ob + 2] = jx2;
      out[ob + 3] = jy2;
      out[ob + 4] = s2[(size_t)b * NPOST + j];
    }
    if (j >= total) {
      size_t ob = (size_t)b * (NPOST * 5) + (size_t)j * 5;
      for (int c = 0; c < 5; ++c) out[ob + c] = 0.f;
    }
  }
}

extern "C" void kernel_launch(void* const* d_in, const int* in_sizes, int n_in,
                              void* d_out, int out_size, void* d_ws, size_t ws_size,
                              hipStream_t stream) {
  const float *x = nullptr, *conv_w = nullptr, *conv_b = nullptr,
              *box_w = nullptr, *box_b = nullptr, *obj_w = nullptr, *obj_b = nullptr;
  for (int i = 0; i < n_in; ++i) {
    switch (in_sizes[i]) {
      case 8388608: x = (const float*)d_in[i]; break;      // 8*256*64*64
      case 589824:  conv_w = (const float*)d_in[i]; break; // 256*256*9
      case 256:     conv_b = (const float*)d_in[i]; break;
      case 9216:    box_w = (const float*)d_in[i]; break;  // 36*256
      case 36:      box_b = (const float*)d_in[i]; break;
      case 2304:    obj_w = (const float*)d_in[i]; break;  // 9*256
      case 9:       obj_b = (const float*)d_in[i]; break;
    }
  }
  float* out = (float*)d_out;

  // Workspace ~39.7 MB (established safe in rounds 0/5)
  char* p = (char*)d_ws;
  auto alloc = [&](size_t n) { char* q = p; p += (n + 255) & ~255ull; return (void*)q; };
  float* feats  = (float*)alloc((size_t)B_ * C_ * HW_ * 4);       // 33.55 MB
  float* tbox   = (float*)alloc((size_t)B_ * 4 * SITES * 4);      // 4.72 MB
  float* scores = (float*)alloc((size_t)B_ * SITES * 4);          // 1.18 MB
  unsigned* Kout = (unsigned*)alloc(B_ * 4);
  int* needEq    = (int*)alloc(B_ * 4);
  int* cnt       = (int*)alloc(B_ * 4);
  int* sel       = (int*)alloc((size_t)B_ * 1024 * 4);
  int* slot_site = (int*)alloc((size_t)B_ * NPOST * 4);
  float* s2      = (float*)alloc((size_t)B_ * NPOST * 4);
  float* b2      = (float*)alloc((size_t)B_ * NPOST * 4 * 4);

  hipLaunchKernelGGL(conv3_shfl, dim3(B_ * C_ * 2), dim3(256), 0, stream,
                     x, conv_w, conv_b, feats);
  hipLaunchKernelGGL(conv1_fused, dim3(B_ * HW_ / 256), dim3(256), 0, stream,
                     feats, box_w, box_b, obj_w, obj_b, tbox, scores);
  hipLaunchKernelGGL(radix_select, dim3(B_), dim3(1024), 0, stream,
                     scores, Kout, needEq, cnt);
  hipLaunchKernelGGL(compact_sel, dim3(B_ * 144), dim3(256), 0, stream,
                     scores, Kout, needEq, cnt, sel);
  hipLaunchKernelGGL(order_sel, dim3(B_), dim3(1024), 0, stream,
                     scores, sel, slot_site, s2);
  hipLaunchKernelGGL(decode_k, dim3((B_ * NPOST + 255) / 256), dim3(256), 0, stream,
                     tbox, slot_site, b2);
  hipLaunchKernelGGL(nms_compact, dim3(B_), dim3(1024), 0, stream, b2, s2, out);
}

// Round 7
// 1339.615 us; speedup vs baseline: 6.1695x; 2.0960x over previous
//
#include <hip/hip_runtime.h>

#define B_ 8
#define C_ 256
#define H_ 64
#define W_ 64
#define HW_ 4096
#define A_ 9
#define SITES 36864      // A_*HW_
#define NPOST 1000
#define XCLIPF 4.1351666f   // (float)4.135166556742356
#define IMGF 1024.0f

__device__ inline unsigned keyf(float v) {
  unsigned u = __float_as_uint(v);
  return (u & 0x80000000u) ? ~u : (u | 0x80000000u);  // ascending uint == ascending float
}

// ---------------- K1: 3x3 conv + bias + relu, bit-exact f32, LDS-FREE ----------------
// (unchanged from round 6 — passing, bit-exact)
__global__ __launch_bounds__(256) void conv3_shfl(
    const float* __restrict__ x, const float* __restrict__ w,
    const float* __restrict__ bias, float* __restrict__ feats) {
#pragma clang fp contract(off)
  int b    = blockIdx.x >> 9;
  int co   = (blockIdx.x >> 1) & 255;
  int half = blockIdx.x & 1;
  int rih  = threadIdx.x >> 3;
  int chunk= threadIdx.x & 7;
  int gr   = (half << 5) + rih;
  int c0   = chunk << 3;
  int trow = gr > 0 ? gr - 1 : 0;
  int brow = gr < 63 ? gr + 1 : 63;
  bool top0 = (gr == 0), bot0 = (gr == 63);
  bool lef0 = (chunk == 0), rig0 = (chunk == 7);

  const float* xb = x + (size_t)b * C_ * HW_;
  const float4* pT = (const float4*)(xb + (size_t)trow * W_ + c0);
  const float4* pM = (const float4*)(xb + (size_t)gr   * W_ + c0);
  const float4* pB = (const float4*)(xb + (size_t)brow * W_ + c0);
  const float* wp = w + (size_t)co * (C_ * 9);

  float acc[8][9];
#pragma unroll
  for (int p = 0; p < 8; ++p)
#pragma unroll
    for (int t = 0; t < 9; ++t) acc[p][t] = 0.f;

  for (int ci = 0; ci < C_; ++ci) {
    float4 tA = pT[0], tB = pT[1];
    float4 mA = pM[0], mB = pM[1];
    float4 bA = pB[0], bB = pB[1];
    pT += HW_ / 4; pM += HW_ / 4; pB += HW_ / 4;

    float T[10], M[10], Bo[10];
    T[1]=tA.x; T[2]=tA.y; T[3]=tA.z; T[4]=tA.w; T[5]=tB.x; T[6]=tB.y; T[7]=tB.z; T[8]=tB.w;
    M[1]=mA.x; M[2]=mA.y; M[3]=mA.z; M[4]=mA.w; M[5]=mB.x; M[6]=mB.y; M[7]=mB.z; M[8]=mB.w;
    Bo[1]=bA.x; Bo[2]=bA.y; Bo[3]=bA.z; Bo[4]=bA.w; Bo[5]=bB.x; Bo[6]=bB.y; Bo[7]=bB.z; Bo[8]=bB.w;
    if (top0) {
#pragma unroll
      for (int j = 1; j <= 8; ++j) T[j] = 0.f;
    }
    if (bot0) {
#pragma unroll
      for (int j = 1; j <= 8; ++j) Bo[j] = 0.f;
    }
    T[0]  = __shfl_up(T[8], 1u);   if (lef0) T[0]  = 0.f;
    T[9]  = __shfl_down(T[1], 1u); if (rig0) T[9]  = 0.f;
    M[0]  = __shfl_up(M[8], 1u);   if (lef0) M[0]  = 0.f;
    M[9]  = __shfl_down(M[1], 1u); if (rig0) M[9]  = 0.f;
    Bo[0] = __shfl_up(Bo[8], 1u);  if (lef0) Bo[0] = 0.f;
    Bo[9] = __shfl_down(Bo[1], 1u);if (rig0) Bo[9] = 0.f;

    float w9[9];
#pragma unroll
    for (int t = 0; t < 9; ++t) w9[t] = wp[ci * 9 + t];

#pragma unroll
    for (int p = 0; p < 8; ++p) {
      acc[p][0] = fmaf(w9[0], T[p],    acc[p][0]);
      acc[p][1] = fmaf(w9[1], T[p+1],  acc[p][1]);
      acc[p][2] = fmaf(w9[2], T[p+2],  acc[p][2]);
      acc[p][3] = fmaf(w9[3], M[p],    acc[p][3]);
      acc[p][4] = fmaf(w9[4], M[p+1],  acc[p][4]);
      acc[p][5] = fmaf(w9[5], M[p+2],  acc[p][5]);
      acc[p][6] = fmaf(w9[6], Bo[p],   acc[p][6]);
      acc[p][7] = fmaf(w9[7], Bo[p+1], acc[p][7]);
      acc[p][8] = fmaf(w9[8], Bo[p+2], acc[p][8]);
    }
  }

  float bv = bias[co];
  float ov[8];
#pragma unroll
  for (int p = 0; p < 8; ++p) {
    float a = 0.f;
#pragma unroll
    for (int t = 0; t < 9; ++t) a = a + acc[p][t];
    a = a + bv;
    ov[p] = a > 0.f ? a : 0.f;
  }
  float4* fo = (float4*)(feats + ((size_t)b * C_ + co) * HW_ + (size_t)gr * W_ + c0);
  fo[0] = make_float4(ov[0], ov[1], ov[2], ov[3]);
  fo[1] = make_float4(ov[4], ov[5], ov[6], ov[7]);
}

// ---------------- K2: fused 1x1 convs (36 box + 9 obj), bit-exact f32 chains ----------------
__global__ __launch_bounds__(256) void conv1_fused(
    const float* __restrict__ feats,
    const float* __restrict__ box_w, const float* __restrict__ box_b,
    const float* __restrict__ obj_w, const float* __restrict__ obj_b,
    float* __restrict__ tbox, float* __restrict__ scores) {
#pragma clang fp contract(off)
  int idx = blockIdx.x * 256 + threadIdx.x;
  int b = idx >> 12;
  int hw = idx & 4095;
  const float* f = feats + (size_t)b * C_ * HW_ + hw;
  float acc[45];
#pragma unroll
  for (int c = 0; c < 45; ++c) acc[c] = 0.f;
  for (int ci = 0; ci < C_; ++ci) {
    float fv = f[(size_t)ci * HW_];
#pragma unroll
    for (int c = 0; c < 36; ++c)
      acc[c] = fmaf(box_w[c * C_ + ci], fv, acc[c]);
#pragma unroll
    for (int a = 0; a < 9; ++a)
      acc[36 + a] = fmaf(obj_w[a * C_ + ci], fv, acc[36 + a]);
  }
#pragma unroll
  for (int c = 0; c < 36; ++c) {
    int k = c / 9, a = c - k * 9;
    tbox[(size_t)b * 4 * SITES + (size_t)k * SITES + (size_t)a * HW_ + hw] = acc[c] + box_b[c];
  }
#pragma unroll
  for (int a = 0; a < 9; ++a)
    scores[(size_t)b * SITES + (size_t)a * HW_ + hw] = acc[36 + a] + obj_b[a];
}

// ---------------- K3: exact radix-select of the 1000th-smallest key per batch ----------------
__global__ __launch_bounds__(1024) void radix_select(
    const float* __restrict__ scores, unsigned* __restrict__ Kout,
    int* __restrict__ needEq, int* __restrict__ cnt, int* __restrict__ eqCnt) {
  int b = blockIdx.x;
  const float* s = scores + (size_t)b * SITES;
  __shared__ unsigned hist[256];
  __shared__ unsigned sh_prefix, sh_mask, sh_cless;
  __shared__ int sh_target;
  if (threadIdx.x == 0) { sh_prefix = 0; sh_mask = 0; sh_target = NPOST - 1; sh_cless = 0; }
  for (int shift = 24; shift >= 0; shift -= 8) {
    if (threadIdx.x < 256) hist[threadIdx.x] = 0;
    __syncthreads();
    unsigned prefix = sh_prefix, mask = sh_mask;
    for (int i = threadIdx.x; i < SITES; i += 1024) {
      unsigned k = keyf(s[i]);
      if ((k & mask) == prefix) atomicAdd(&hist[(k >> shift) & 255u], 1u);
    }
    __syncthreads();
    if (threadIdx.x == 0) {
      unsigned cum = 0; int t = sh_target; int v = 0;
      for (; v < 256; ++v) {
        unsigned h = hist[v];
        if (cum + h > (unsigned)t) break;
        cum += h;
      }
      sh_prefix |= ((unsigned)v) << shift;
      sh_mask   |= 0xFFu << shift;
      sh_target  = t - (int)cum;
      sh_cless  += cum;
    }
    __syncthreads();
  }
  if (threadIdx.x == 0) {
    Kout[b] = sh_prefix;
    needEq[b] = NPOST - (int)sh_cless;   // # of key==K items to take (smallest site indices)
    cnt[b] = 0;
    eqCnt[b] = 0;
  }
}

// ---------------- K4: compact k<K sites; collect k==K sites (NO serial scans) ----------------
__global__ __launch_bounds__(256) void compact_sel(
    const float* __restrict__ scores, const unsigned* __restrict__ Kout,
    int* __restrict__ cnt, int* __restrict__ sel,
    int* __restrict__ eqCnt, int* __restrict__ eqList) {
  int b = blockIdx.x / 144;
  int i = (blockIdx.x % 144) * 256 + threadIdx.x;
  unsigned K = Kout[b];
  unsigned k = keyf(scores[(size_t)b * SITES + i]);
  if (k < K) {
    int pos = atomicAdd(&cnt[b], 1);
    sel[b * 1024 + pos] = i;               // arbitrary order: order_sel re-sorts
  } else if (k == K) {
    int e = atomicAdd(&eqCnt[b], 1);
    if (e < 4096) eqList[b * 4096 + e] = i;
  }
}

// ---------------- K4b: take the needEq smallest-index equal-key sites ----------------
// E is tiny (usually 1); O(E^2) rank in one block per batch
__global__ __launch_bounds__(256) void fix_eq(
    const int* __restrict__ cnt, const int* __restrict__ needEq,
    const int* __restrict__ eqCnt, const int* __restrict__ eqList,
    int* __restrict__ sel) {
  int b = blockIdx.x;
  int E = eqCnt[b]; if (E > 4096) E = 4096;
  int need = needEq[b];
  int base = cnt[b];                        // == count_less
  const int* el = eqList + b * 4096;
  for (int t = threadIdx.x; t < E; t += 256) {
    int site = el[t];
    int rank = 0;
    for (int q = 0; q < E; ++q) rank += (el[q] < site);
    if (rank < need) sel[b * 1024 + base + rank] = site;
  }
}

// ---------------- K5: exact descending order of the selected 1000 (tie: site index asc) ----------------
__global__ __launch_bounds__(1024) void order_sel(
    const float* __restrict__ scores, const int* __restrict__ sel,
    int* __restrict__ slot_site, float* __restrict__ s2) {
  int b = blockIdx.x;
  int r = threadIdx.x;
  __shared__ float ss[NPOST];
  __shared__ int st[NPOST];
  if (r < NPOST) {
    int site = sel[b * 1024 + r];
    st[r] = site;
    ss[r] = scores[(size_t)b * SITES + site];
  }
  __syncthreads();
  if (r < NPOST) {
    float sr = ss[r]; int sir = st[r];
    int d = 0;
    for (int q = 0; q < NPOST; ++q) {
      float sq = ss[q];
      d += (int)((sq > sr) || (sq == sr && st[q] < sir));
    }
    slot_site[b * NPOST + d] = sir;
    s2[(size_t)b * NPOST + d] = sr;
  }
}

// ---------------- K6: faithful f32 decode of the 1000 slots ----------------
__global__ __launch_bounds__(256) void decode_k(
    const float* __restrict__ tbox, const int* __restrict__ slot_site,
    float* __restrict__ b2) {
#pragma clang fp contract(off)
  int idx = blockIdx.x * 256 + threadIdx.x;
  if (idx >= B_ * NPOST) return;
  int b = idx / NPOST, d = idx - b * NPOST;
  int site = slot_site[(size_t)b * NPOST + d];
  int a = site / HW_;
  int hw = site - a * HW_;
  int h = hw / W_, wc = hw - h * W_;
  int sidx = a / 3, ridx = a - sidx * 3;
  float scale = (sidx == 0) ? 128.f : ((sidx == 1) ? 256.f : 512.f);
  float ratio = (ridx == 0) ? 0.5f : ((ridx == 1) ? 1.0f : 2.0f);
  float sq = sqrtf(ratio);
  float wsa = scale / sq;
  float hsa = scale * sq;
  float cx = ((float)wc + 0.5f) * 16.f;
  float cy = ((float)h + 0.5f) * 16.f;
  float ax1 = cx - wsa * 0.5f;
  float ay1 = cy - hsa * 0.5f;
  float ax2 = cx + wsa * 0.5f;
  float ay2 = cy + hsa * 0.5f;
  float aw = ax2 - ax1, ah = ay2 - ay1;
  float m1 = 0.5f * aw, m2 = 0.5f * ah;
  float acx = ax1 + m1, acy = ay1 + m2;
  const float* tb = tbox + (size_t)b * 4 * SITES + site;
  float t0 = tb[0];
  float t1 = tb[SITES];
  float t2 = tb[2 * (size_t)SITES];
  float t3 = tb[3 * (size_t)SITES];
  if (t2 < -XCLIPF) t2 = -XCLIPF;
  if (t2 > XCLIPF) t2 = XCLIPF;
  if (t3 < -XCLIPF) t3 = -XCLIPF;
  if (t3 > XCLIPF) t3 = XCLIPF;
  float pm0 = t0 * aw;  float pcx = pm0 + acx;
  float pm1 = t1 * ah;  float pcy = pm1 + acy;
  float pw = expf(t2) * aw;
  float ph = expf(t3) * ah;
  float hw0 = 0.5f * pw, hh0 = 0.5f * ph;
  float x1 = pcx - hw0, y1 = pcy - hh0;
  float x2 = pcx + hw0, y2 = pcy + hh0;
  x1 = x1 < 0.f ? 0.f : (x1 > IMGF ? IMGF : x1);
  y1 = y1 < 0.f ? 0.f : (y1 > IMGF ? IMGF : y1);
  x2 = x2 < 0.f ? 0.f : (x2 > IMGF ? IMGF : x2);
  y2 = y2 < 0.f ? 0.f : (y2 > IMGF ? IMGF : y2);
  float* o = b2 + ((size_t)b * NPOST + d) * 4;
  o[0] = x1; o[1] = y1; o[2] = x2; o[3] = y2;
}

// ---------------- K7a: suppression bitmask (j > i && IoU > 0.7), f32, exact op order ----------------
// grid B_*63 blocks, 256 threads = 16 rows x 16 words of 64 bits
__global__ __launch_bounds__(256) void mask_kernel(
    const float* __restrict__ b2, unsigned long long* __restrict__ sup) {
#pragma clang fp contract(off)
  int b = blockIdx.x / 63;
  int i0 = (blockIdx.x % 63) * 16;
  __shared__ float bs[NPOST * 4];
  __shared__ float area[NPOST];
  for (int t = threadIdx.x; t < NPOST * 4; t += 256) bs[t] = b2[(size_t)b * NPOST * 4 + t];
  __syncthreads();
  for (int t = threadIdx.x; t < NPOST; t += 256)
    area[t] = (bs[t * 4 + 2] - bs[t * 4]) * (bs[t * 4 + 3] - bs[t * 4 + 1]);
  __syncthreads();
  int i = i0 + (threadIdx.x >> 4);
  int wd = threadIdx.x & 15;
  if (i >= NPOST) return;
  float ax1 = bs[i * 4], ay1 = bs[i * 4 + 1], ax2 = bs[i * 4 + 2], ay2 = bs[i * 4 + 3];
  float aa = area[i];
  unsigned long long m = 0;
  for (int bit = 0; bit < 64; ++bit) {
    int j = wd * 64 + bit;
    if (j > i && j < NPOST) {
      // identical op order to the validated literal NMS (row value first)
      float lx = fmaxf(ax1, bs[j * 4]);
      float ly = fmaxf(ay1, bs[j * 4 + 1]);
      float rx = fminf(ax2, bs[j * 4 + 2]);
      float ry = fminf(ay2, bs[j * 4 + 3]);
      float iw = rx - lx; if (iw < 0.f) iw = 0.f;
      float ih = ry - ly; if (ih < 0.f) ih = 0.f;
      float inter = iw * ih;
      float denom = (aa + area[j]) - inter;
      float iou = inter / denom;
      if (iou > 0.7f) m |= 1ull << bit;
    }
  }
  sup[((size_t)b * NPOST + i) * 16 + wd] = m;
}

// ---------------- K7b: wave-synchronous NMS scan + compaction + zero fill ----------------
// grid B_ blocks, 64 threads; keep mask in registers (lane L owns word L, L<16); row prefetch
__global__ __launch_bounds__(64) void nms_out(
    const unsigned long long* __restrict__ sup, const float* __restrict__ b2,
    const float* __restrict__ s2, float* __restrict__ out) {
  int b = blockIdx.x;
  int lane = threadIdx.x;
  unsigned long long kw = 0;
  if (lane < 16) kw = (lane < 15) ? ~0ull : ((1ull << 40) - 1);  // bits 960..999 valid
  const unsigned long long* ms = sup + (size_t)b * NPOST * 16;
  unsigned long long m_cur = (lane < 16) ? ms[lane] : 0ull;
  for (int i = 0; i < NPOST; ++i) {
    unsigned long long m_nxt = (i + 1 < NPOST && lane < 16) ? ms[(size_t)(i + 1) * 16 + lane] : 0ull;
    unsigned long long w = __shfl(kw, i >> 6, 64);   // broadcast word holding bit i
    if ((w >> (i & 63)) & 1ull) {                    // wave-uniform branch
      if (lane < 16) kw &= ~m_cur;                   // bit i never set in row i (j>i only)
    }
    m_cur = m_nxt;
  }
  __shared__ unsigned long long keeps[16];
  if (lane < 16) keeps[lane] = kw;
  __syncthreads();
  int total = 0;
#pragma unroll
  for (int k = 0; k < 16; ++k) total += __popcll(keeps[k]);
  for (int i = lane; i < NPOST; i += 64) {
    int w = i >> 6;
    int before = 0;
    for (int k = 0; k < w; ++k) before += __popcll(keeps[k]);
    before += __popcll(keeps[w] & ((1ull << (i & 63)) - 1));
    bool kept = (keeps[w] >> (i & 63)) & 1ull;
    if (kept) {
      size_t ob = (size_t)b * (NPOST * 5) + (size_t)before * 5;
      const float* src = b2 + ((size_t)b * NPOST + i) * 4;
      out[ob + 0] = src[0];
      out[ob + 1] = src[1];
      out[ob + 2] = src[2];
      out[ob + 3] = src[3];
      out[ob + 4] = s2[(size_t)b * NPOST + i];
    }
    if (i >= total) {
      size_t ob = (size_t)b * (NPOST * 5) + (size_t)i * 5;
      for (int c = 0; c < 5; ++c) out[ob + c] = 0.f;
    }
  }
}

extern "C" void kernel_launch(void* const* d_in, const int* in_sizes, int n_in,
                              void* d_out, int out_size, void* d_ws, size_t ws_size,
                              hipStream_t stream) {
  const float *x = nullptr, *conv_w = nullptr, *conv_b = nullptr,
              *box_w = nullptr, *box_b = nullptr, *obj_w = nullptr, *obj_b = nullptr;
  for (int i = 0; i < n_in; ++i) {
    switch (in_sizes[i]) {
      case 8388608: x = (const float*)d_in[i]; break;
      case 589824:  conv_w = (const float*)d_in[i]; break;
      case 256:     conv_b = (const float*)d_in[i]; break;
      case 9216:    box_w = (const float*)d_in[i]; break;
      case 36:      box_b = (const float*)d_in[i]; break;
      case 2304:    obj_w = (const float*)d_in[i]; break;
      case 9:       obj_b = (const float*)d_in[i]; break;
    }
  }
  float* out = (float*)d_out;

  char* p = (char*)d_ws;
  auto alloc = [&](size_t n) { char* q = p; p += (n + 255) & ~255ull; return (void*)q; };
  float* feats  = (float*)alloc((size_t)B_ * C_ * HW_ * 4);       // 33.55 MB
  float* tbox   = (float*)alloc((size_t)B_ * 4 * SITES * 4);      // 4.72 MB
  float* scores = (float*)alloc((size_t)B_ * SITES * 4);          // 1.18 MB
  unsigned* Kout = (unsigned*)alloc(B_ * 4);
  int* needEq    = (int*)alloc(B_ * 4);
  int* cnt       = (int*)alloc(B_ * 4);
  int* eqCnt     = (int*)alloc(B_ * 4);
  int* eqList    = (int*)alloc((size_t)B_ * 4096 * 4);
  int* sel       = (int*)alloc((size_t)B_ * 1024 * 4);
  int* slot_site = (int*)alloc((size_t)B_ * NPOST * 4);
  float* s2      = (float*)alloc((size_t)B_ * NPOST * 4);
  float* b2      = (float*)alloc((size_t)B_ * NPOST * 4 * 4);
  unsigned long long* sup = (unsigned long long*)alloc((size_t)B_ * NPOST * 16 * 8); // 1.02 MB

  hipLaunchKernelGGL(conv3_shfl, dim3(B_ * C_ * 2), dim3(256), 0, stream,
                     x, conv_w, conv_b, feats);
  hipLaunchKernelGGL(conv1_fused, dim3(B_ * HW_ / 256), dim3(256), 0, stream,
                     feats, box_w, box_b, obj_w, obj_b, tbox, scores);
  hipLaunchKernelGGL(radix_select, dim3(B_), dim3(1024), 0, stream,
                     scores, Kout, needEq, cnt, eqCnt);
  hipLaunchKernelGGL(compact_sel, dim3(B_ * 144), dim3(256), 0, stream,
                     scores, Kout, cnt, sel, eqCnt, eqList);
  hipLaunchKernelGGL(fix_eq, dim3(B_), dim3(256), 0, stream,
                     cnt, needEq, eqCnt, eqList, sel);
  hipLaunchKernelGGL(order_sel, dim3(B_), dim3(1024), 0, stream,
                     scores, sel, slot_site, s2);
  hipLaunchKernelGGL(decode_k, dim3((B_ * NPOST + 255) / 256), dim3(256), 0, stream,
                     tbox, slot_site, b2);
  hipLaunchKernelGGL(mask_kernel, dim3(B_ * 63), dim3(256), 0, stream, b2, sup);
  hipLaunchKernelGGL(nms_out, dim3(B_), dim3(64), 0, stream, sup, b2, s2, out);
}

// Round 8
// 1245.453 us; speedup vs baseline: 6.6360x; 1.0756x over previous
//
#include <hip/hip_runtime.h>

#define B_ 8
#define C_ 256
#define H_ 64
#define W_ 64
#define HW_ 4096
#define A_ 9
#define SITES 36864      // A_*HW_
#define NPOST 1000
#define XCLIPF 4.1351666f   // (float)4.135166556742356
#define IMGF 1024.0f

__device__ inline unsigned keyf(float v) {
  unsigned u = __float_as_uint(v);
  return (u & 0x80000000u) ? ~u : (u | 0x80000000u);  // ascending uint == ascending float
}

// ---------------- K1: 3x3 conv + bias + relu, bit-exact f32, 2 rows/thread ----------------
// Exact op order preserved (identical chains to the round-6/7 passing kernels):
// per pixel, 9 independent fmaf chains over ci ascending; tap-ordered left-assoc sum;
// zero-row taps are exact +0 no-ops. Vertical boundary rows come from a zeroed ws row
// via per-lane stride-0 pointers (no cndmask); horizontal halo via __shfl + edge cndmask.
// grid: B_*C_ blocks; 256 threads = 32 row-pairs x 8 chunks; 16 px/thread.
__global__ __launch_bounds__(256, 2) void conv3_strip(
    const float* __restrict__ x, const float* __restrict__ w,
    const float* __restrict__ bias, const float* __restrict__ zrow,
    float* __restrict__ feats) {
#pragma clang fp contract(off)
  int b  = blockIdx.x >> 8;
  int co = blockIdx.x & 255;
  int rih   = threadIdx.x >> 3;        // 0..31
  int chunk = threadIdx.x & 7;         // 0..7
  int r0 = rih << 1;                   // 0,2,...,62
  int c0 = chunk << 3;
  bool lef0 = (chunk == 0), rig0 = (chunk == 7);
  bool topz = (rih == 0), botz = (rih == 31);

  const float* xb = x + (size_t)b * C_ * HW_;
  const float* pT  = topz ? zrow : (xb + (ptrdiff_t)(r0 - 1) * W_ + c0);
  const float* pM0 = xb + (size_t)r0 * W_ + c0;
  const float* pM1 = xb + (size_t)(r0 + 1) * W_ + c0;
  const float* pB  = botz ? zrow : (xb + (size_t)(r0 + 2) * W_ + c0);
  ptrdiff_t sT = topz ? 0 : HW_;       // per-lane stride (floats)
  ptrdiff_t sB = botz ? 0 : HW_;
  const float* wp = w + (size_t)co * (C_ * 9);

  float acc0[8][9], acc1[8][9];
#pragma unroll
  for (int p = 0; p < 8; ++p)
#pragma unroll
    for (int t = 0; t < 9; ++t) { acc0[p][t] = 0.f; acc1[p][t] = 0.f; }

  for (int ci = 0; ci < C_; ++ci) {
    float4 tA  = ((const float4*)pT)[0],  tB4 = ((const float4*)pT)[1];
    float4 m0A = ((const float4*)pM0)[0], m0B = ((const float4*)pM0)[1];
    float4 m1A = ((const float4*)pM1)[0], m1B = ((const float4*)pM1)[1];
    float4 bA  = ((const float4*)pB)[0],  bB4 = ((const float4*)pB)[1];
    pT += sT; pM0 += HW_; pM1 += HW_; pB += sB;

    float T[10], M0[10], M1[10], Bo[10];
    T[1]=tA.x;  T[2]=tA.y;  T[3]=tA.z;  T[4]=tA.w;  T[5]=tB4.x;  T[6]=tB4.y;  T[7]=tB4.z;  T[8]=tB4.w;
    M0[1]=m0A.x; M0[2]=m0A.y; M0[3]=m0A.z; M0[4]=m0A.w; M0[5]=m0B.x; M0[6]=m0B.y; M0[7]=m0B.z; M0[8]=m0B.w;
    M1[1]=m1A.x; M1[2]=m1A.y; M1[3]=m1A.z; M1[4]=m1A.w; M1[5]=m1B.x; M1[6]=m1B.y; M1[7]=m1B.z; M1[8]=m1B.w;
    Bo[1]=bA.x; Bo[2]=bA.y; Bo[3]=bA.z; Bo[4]=bA.w; Bo[5]=bB4.x; Bo[6]=bB4.y; Bo[7]=bB4.z; Bo[8]=bB4.w;

    T[0]  = __shfl_up(T[8], 1u);    if (lef0) T[0]  = 0.f;
    T[9]  = __shfl_down(T[1], 1u);  if (rig0) T[9]  = 0.f;
    M0[0] = __shfl_up(M0[8], 1u);   if (lef0) M0[0] = 0.f;
    M0[9] = __shfl_down(M0[1], 1u); if (rig0) M0[9] = 0.f;
    M1[0] = __shfl_up(M1[8], 1u);   if (lef0) M1[0] = 0.f;
    M1[9] = __shfl_down(M1[1], 1u); if (rig0) M1[9] = 0.f;
    Bo[0] = __shfl_up(Bo[8], 1u);   if (lef0) Bo[0] = 0.f;
    Bo[9] = __shfl_down(Bo[1], 1u); if (rig0) Bo[9] = 0.f;

    float w9[9];
#pragma unroll
    for (int t = 0; t < 9; ++t) w9[t] = wp[ci * 9 + t];   // wave-uniform -> s_load

#pragma unroll
    for (int p = 0; p < 8; ++p) {
      acc0[p][0] = fmaf(w9[0], T[p],     acc0[p][0]);
      acc0[p][1] = fmaf(w9[1], T[p+1],   acc0[p][1]);
      acc0[p][2] = fmaf(w9[2], T[p+2],   acc0[p][2]);
      acc0[p][3] = fmaf(w9[3], M0[p],    acc0[p][3]);
      acc0[p][4] = fmaf(w9[4], M0[p+1],  acc0[p][4]);
      acc0[p][5] = fmaf(w9[5], M0[p+2],  acc0[p][5]);
      acc0[p][6] = fmaf(w9[6], M1[p],    acc0[p][6]);
      acc0[p][7] = fmaf(w9[7], M1[p+1],  acc0[p][7]);
      acc0[p][8] = fmaf(w9[8], M1[p+2],  acc0[p][8]);
      acc1[p][0] = fmaf(w9[0], M0[p],    acc1[p][0]);
      acc1[p][1] = fmaf(w9[1], M0[p+1],  acc1[p][1]);
      acc1[p][2] = fmaf(w9[2], M0[p+2],  acc1[p][2]);
      acc1[p][3] = fmaf(w9[3], M1[p],    acc1[p][3]);
      acc1[p][4] = fmaf(w9[4], M1[p+1],  acc1[p][4]);
      acc1[p][5] = fmaf(w9[5], M1[p+2],  acc1[p][5]);
      acc1[p][6] = fmaf(w9[6], Bo[p],    acc1[p][6]);
      acc1[p][7] = fmaf(w9[7], Bo[p+1],  acc1[p][7]);
      acc1[p][8] = fmaf(w9[8], Bo[p+2],  acc1[p][8]);
    }
  }

  float bv = bias[co];
  float ov0[8], ov1[8];
#pragma unroll
  for (int p = 0; p < 8; ++p) {
    float a = 0.f;
#pragma unroll
    for (int t = 0; t < 9; ++t) a = a + acc0[p][t];  // tap-ordered, left-assoc
    a = a + bv;
    ov0[p] = a > 0.f ? a : 0.f;
    float c = 0.f;
#pragma unroll
    for (int t = 0; t < 9; ++t) c = c + acc1[p][t];
    c = c + bv;
    ov1[p] = c > 0.f ? c : 0.f;
  }
  float* fbase = feats + ((size_t)b * C_ + co) * HW_;
  float4* fo0 = (float4*)(fbase + (size_t)r0 * W_ + c0);
  float4* fo1 = (float4*)(fbase + (size_t)(r0 + 1) * W_ + c0);
  fo0[0] = make_float4(ov0[0], ov0[1], ov0[2], ov0[3]);
  fo0[1] = make_float4(ov0[4], ov0[5], ov0[6], ov0[7]);
  fo1[0] = make_float4(ov1[0], ov1[1], ov1[2], ov1[3]);
  fo1[1] = make_float4(ov1[4], ov1[5], ov1[6], ov1[7]);
}

// ---------------- K2: fused 1x1 convs (36 box + 9 obj), bit-exact f32 chains ----------------
__global__ __launch_bounds__(256) void conv1_fused(
    const float* __restrict__ feats,
    const float* __restrict__ box_w, const float* __restrict__ box_b,
    const float* __restrict__ obj_w, const float* __restrict__ obj_b,
    float* __restrict__ tbox, float* __restrict__ scores) {
#pragma clang fp contract(off)
  int idx = blockIdx.x * 256 + threadIdx.x;
  int b = idx >> 12;
  int hw = idx & 4095;
  const float* f = feats + (size_t)b * C_ * HW_ + hw;
  float acc[45];
#pragma unroll
  for (int c = 0; c < 45; ++c) acc[c] = 0.f;
  for (int ci = 0; ci < C_; ++ci) {
    float fv = f[(size_t)ci * HW_];
#pragma unroll
    for (int c = 0; c < 36; ++c)
      acc[c] = fmaf(box_w[c * C_ + ci], fv, acc[c]);
#pragma unroll
    for (int a = 0; a < 9; ++a)
      acc[36 + a] = fmaf(obj_w[a * C_ + ci], fv, acc[36 + a]);
  }
#pragma unroll
  for (int c = 0; c < 36; ++c) {
    int k = c / 9, a = c - k * 9;
    tbox[(size_t)b * 4 * SITES + (size_t)k * SITES + (size_t)a * HW_ + hw] = acc[c] + box_b[c];
  }
#pragma unroll
  for (int a = 0; a < 9; ++a)
    scores[(size_t)b * SITES + (size_t)a * HW_ + hw] = acc[36 + a] + obj_b[a];
}

// ---------------- K3: exact radix-select of the 1000th-smallest key per batch ----------------
__global__ __launch_bounds__(1024) void radix_select(
    const float* __restrict__ scores, unsigned* __restrict__ Kout,
    int* __restrict__ needEq, int* __restrict__ cnt, int* __restrict__ eqCnt) {
  int b = blockIdx.x;
  const float* s = scores + (size_t)b * SITES;
  __shared__ unsigned hist[256];
  __shared__ unsigned sh_prefix, sh_mask, sh_cless;
  __shared__ int sh_target;
  if (threadIdx.x == 0) { sh_prefix = 0; sh_mask = 0; sh_target = NPOST - 1; sh_cless = 0; }
  for (int shift = 24; shift >= 0; shift -= 8) {
    if (threadIdx.x < 256) hist[threadIdx.x] = 0;
    __syncthreads();
    unsigned prefix = sh_prefix, mask = sh_mask;
    for (int i = threadIdx.x; i < SITES; i += 1024) {
      unsigned k = keyf(s[i]);
      if ((k & mask) == prefix) atomicAdd(&hist[(k >> shift) & 255u], 1u);
    }
    __syncthreads();
    if (threadIdx.x == 0) {
      unsigned cum = 0; int t = sh_target; int v = 0;
      for (; v < 256; ++v) {
        unsigned h = hist[v];
        if (cum + h > (unsigned)t) break;
        cum += h;
      }
      sh_prefix |= ((unsigned)v) << shift;
      sh_mask   |= 0xFFu << shift;
      sh_target  = t - (int)cum;
      sh_cless  += cum;
    }
    __syncthreads();
  }
  if (threadIdx.x == 0) {
    Kout[b] = sh_prefix;
    needEq[b] = NPOST - (int)sh_cless;
    cnt[b] = 0;
    eqCnt[b] = 0;
  }
}

// ---------------- K4: compact k<K sites; collect k==K sites ----------------
__global__ __launch_bounds__(256) void compact_sel(
    const float* __restrict__ scores, const unsigned* __restrict__ Kout,
    int* __restrict__ cnt, int* __restrict__ sel,
    int* __restrict__ eqCnt, int* __restrict__ eqList) {
  int b = blockIdx.x / 144;
  int i = (blockIdx.x % 144) * 256 + threadIdx.x;
  unsigned K = Kout[b];
  unsigned k = keyf(scores[(size_t)b * SITES + i]);
  if (k < K) {
    int pos = atomicAdd(&cnt[b], 1);
    sel[b * 1024 + pos] = i;               // arbitrary order: order_decode re-sorts
  } else if (k == K) {
    int e = atomicAdd(&eqCnt[b], 1);
    if (e < 4096) eqList[b * 4096 + e] = i;
  }
}

// ---------------- K4b: take the needEq smallest-index equal-key sites ----------------
__global__ __launch_bounds__(256) void fix_eq(
    const int* __restrict__ cnt, const int* __restrict__ needEq,
    const int* __restrict__ eqCnt, const int* __restrict__ eqList,
    int* __restrict__ sel) {
  int b = blockIdx.x;
  int E = eqCnt[b]; if (E > 4096) E = 4096;
  int need = needEq[b];
  int base = cnt[b];
  const int* el = eqList + b * 4096;
  for (int t = threadIdx.x; t < E; t += 256) {
    int site = el[t];
    int rank = 0;
    for (int q = 0; q < E; ++q) rank += (el[q] < site);
    if (rank < need) sel[b * 1024 + base + rank] = site;
  }
}

// ---------------- K5: descending order of the selected 1000 + fused decode ----------------
__global__ __launch_bounds__(1024) void order_decode(
    const float* __restrict__ scores, const int* __restrict__ sel,
    const float* __restrict__ tbox, float* __restrict__ s2, float* __restrict__ b2) {
#pragma clang fp contract(off)
  int b = blockIdx.x;
  int r = threadIdx.x;
  __shared__ float ss[NPOST];
  __shared__ int st[NPOST];
  if (r < NPOST) {
    int site = sel[b * 1024 + r];
    st[r] = site;
    ss[r] = scores[(size_t)b * SITES + site];
  }
  __syncthreads();
  if (r < NPOST) {
    float sr = ss[r]; int sir = st[r];
    int d = 0;
    for (int q = 0; q < NPOST; ++q) {
      float sq = ss[q];
      d += (int)((sq > sr) || (sq == sr && st[q] < sir));
    }
    s2[(size_t)b * NPOST + d] = sr;
    // ---- decode (verbatim op order from the validated decode_k) ----
    int site = sir;
    int a = site / HW_;
    int hw = site - a * HW_;
    int h = hw / W_, wc = hw - h * W_;
    int sidx = a / 3, ridx = a - sidx * 3;
    float scale = (sidx == 0) ? 128.f : ((sidx == 1) ? 256.f : 512.f);
    float ratio = (ridx == 0) ? 0.5f : ((ridx == 1) ? 1.0f : 2.0f);
    float sq = sqrtf(ratio);
    float wsa = scale / sq;
    float hsa = scale * sq;
    float cx = ((float)wc + 0.5f) * 16.f;
    float cy = ((float)h + 0.5f) * 16.f;
    float ax1 = cx - wsa * 0.5f;
    float ay1 = cy - hsa * 0.5f;
    float ax2 = cx + wsa * 0.5f;
    float ay2 = cy + hsa * 0.5f;
    float aw = ax2 - ax1, ah = ay2 - ay1;
    float m1 = 0.5f * aw, m2 = 0.5f * ah;
    float acx = ax1 + m1, acy = ay1 + m2;
    const float* tb = tbox + (size_t)b * 4 * SITES + site;
    float t0 = tb[0];
    float t1 = tb[SITES];
    float t2 = tb[2 * (size_t)SITES];
    float t3 = tb[3 * (size_t)SITES];
    if (t2 < -XCLIPF) t2 = -XCLIPF;
    if (t2 > XCLIPF) t2 = XCLIPF;
    if (t3 < -XCLIPF) t3 = -XCLIPF;
    if (t3 > XCLIPF) t3 = XCLIPF;
    float pm0 = t0 * aw;  float pcx = pm0 + acx;
    float pm1 = t1 * ah;  float pcy = pm1 + acy;
    float pw = expf(t2) * aw;
    float ph = expf(t3) * ah;
    float hw0 = 0.5f * pw, hh0 = 0.5f * ph;
    float x1 = pcx - hw0, y1 = pcy - hh0;
    float x2 = pcx + hw0, y2 = pcy + hh0;
    x1 = x1 < 0.f ? 0.f : (x1 > IMGF ? IMGF : x1);
    y1 = y1 < 0.f ? 0.f : (y1 > IMGF ? IMGF : y1);
    x2 = x2 < 0.f ? 0.f : (x2 > IMGF ? IMGF : x2);
    y2 = y2 < 0.f ? 0.f : (y2 > IMGF ? IMGF : y2);
    float* o = b2 + ((size_t)b * NPOST + d) * 4;
    o[0] = x1; o[1] = y1; o[2] = x2; o[3] = y2;
  }
}

// ---------------- K6a: suppression bitmask (j > i && IoU > 0.7), f32, exact op order ----------------
__global__ __launch_bounds__(256) void mask_kernel(
    const float* __restrict__ b2, unsigned long long* __restrict__ sup) {
#pragma clang fp contract(off)
  int b = blockIdx.x / 63;
  int i0 = (blockIdx.x % 63) * 16;
  __shared__ float bs[NPOST * 4];
  __shared__ float area[NPOST];
  for (int t = threadIdx.x; t < NPOST * 4; t += 256) bs[t] = b2[(size_t)b * NPOST * 4 + t];
  __syncthreads();
  for (int t = threadIdx.x; t < NPOST; t += 256)
    area[t] = (bs[t * 4 + 2] - bs[t * 4]) * (bs[t * 4 + 3] - bs[t * 4 + 1]);
  __syncthreads();
  int i = i0 + (threadIdx.x >> 4);
  int wd = threadIdx.x & 15;
  if (i >= NPOST) return;
  float ax1 = bs[i * 4], ay1 = bs[i * 4 + 1], ax2 = bs[i * 4 + 2], ay2 = bs[i * 4 + 3];
  float aa = area[i];
  unsigned long long m = 0;
  for (int bit = 0; bit < 64; ++bit) {
    int j = wd * 64 + bit;
    if (j > i && j < NPOST) {
      float lx = fmaxf(ax1, bs[j * 4]);
      float ly = fmaxf(ay1, bs[j * 4 + 1]);
      float rx = fminf(ax2, bs[j * 4 + 2]);
      float ry = fminf(ay2, bs[j * 4 + 3]);
      float iw = rx - lx; if (iw < 0.f) iw = 0.f;
      float ih = ry - ly; if (ih < 0.f) ih = 0.f;
      float inter = iw * ih;
      float denom = (aa + area[j]) - inter;
      float iou = inter / denom;
      if (iou > 0.7f) m |= 1ull << bit;
    }
  }
  sup[((size_t)b * NPOST + i) * 16 + wd] = m;
}

// ---------------- K6b: wave-synchronous NMS scan + compaction + zero fill ----------------
__global__ __launch_bounds__(64) void nms_out(
    const unsigned long long* __restrict__ sup, const float* __restrict__ b2,
    const float* __restrict__ s2, float* __restrict__ out) {
  int b = blockIdx.x;
  int lane = threadIdx.x;
  unsigned long long kw = 0;
  if (lane < 16) kw = (lane < 15) ? ~0ull : ((1ull << 40) - 1);  // bits 960..999 valid
  const unsigned long long* ms = sup + (size_t)b * NPOST * 16;
  unsigned long long m_cur = (lane < 16) ? ms[lane] : 0ull;
  for (int i = 0; i < NPOST; ++i) {
    unsigned long long m_nxt = (i + 1 < NPOST && lane < 16) ? ms[(size_t)(i + 1) * 16 + lane] : 0ull;
    unsigned long long w = __shfl(kw, i >> 6, 64);
    if ((w >> (i & 63)) & 1ull) {
      if (lane < 16) kw &= ~m_cur;
    }
    m_cur = m_nxt;
  }
  __shared__ unsigned long long keeps[16];
  if (lane < 16) keeps[lane] = kw;
  __syncthreads();
  int total = 0;
#pragma unroll
  for (int k = 0; k < 16; ++k) total += __popcll(keeps[k]);
  for (int i = lane; i < NPOST; i += 64) {
    int w = i >> 6;
    int before = 0;
    for (int k = 0; k < w; ++k) before += __popcll(keeps[k]);
    before += __popcll(keeps[w] & ((1ull << (i & 63)) - 1));
    bool kept = (keeps[w] >> (i & 63)) & 1ull;
    if (kept) {
      size_t ob = (size_t)b * (NPOST * 5) + (size_t)before * 5;
      const float* src = b2 + ((size_t)b * NPOST + i) * 4;
      out[ob + 0] = src[0];
      out[ob + 1] = src[1];
      out[ob + 2] = src[2];
      out[ob + 3] = src[3];
      out[ob + 4] = s2[(size_t)b * NPOST + i];
    }
    if (i >= total) {
      size_t ob = (size_t)b * (NPOST * 5) + (size_t)i * 5;
      for (int c = 0; c < 5; ++c) out[ob + c] = 0.f;
    }
  }
}

extern "C" void kernel_launch(void* const* d_in, const int* in_sizes, int n_in,
                              void* d_out, int out_size, void* d_ws, size_t ws_size,
                              hipStream_t stream) {
  const float *x = nullptr, *conv_w = nullptr, *conv_b = nullptr,
              *box_w = nullptr, *box_b = nullptr, *obj_w = nullptr, *obj_b = nullptr;
  for (int i = 0; i < n_in; ++i) {
    switch (in_sizes[i]) {
      case 8388608: x = (const float*)d_in[i]; break;
      case 589824:  conv_w = (const float*)d_in[i]; break;
      case 256:     conv_b = (const float*)d_in[i]; break;
      case 9216:    box_w = (const float*)d_in[i]; break;
      case 36:      box_b = (const float*)d_in[i]; break;
      case 2304:    obj_w = (const float*)d_in[i]; break;
      case 9:       obj_b = (const float*)d_in[i]; break;
    }
  }
  float* out = (float*)d_out;

  char* p = (char*)d_ws;
  auto alloc = [&](size_t n) { char* q = p; p += (n + 255) & ~255ull; return (void*)q; };
  float* feats  = (float*)alloc((size_t)B_ * C_ * HW_ * 4);       // 33.55 MB
  float* tbox   = (float*)alloc((size_t)B_ * 4 * SITES * 4);      // 4.72 MB
  float* scores = (float*)alloc((size_t)B_ * SITES * 4);          // 1.18 MB
  float* zrow   = (float*)alloc(256);                              // zero halo row
  unsigned* Kout = (unsigned*)alloc(B_ * 4);
  int* needEq    = (int*)alloc(B_ * 4);
  int* cnt       = (int*)alloc(B_ * 4);
  int* eqCnt     = (int*)alloc(B_ * 4);
  int* eqList    = (int*)alloc((size_t)B_ * 4096 * 4);
  int* sel       = (int*)alloc((size_t)B_ * 1024 * 4);
  float* s2      = (float*)alloc((size_t)B_ * NPOST * 4);
  float* b2      = (float*)alloc((size_t)B_ * NPOST * 4 * 4);
  unsigned long long* sup = (unsigned long long*)alloc((size_t)B_ * NPOST * 16 * 8); // 1.02 MB

  hipMemsetAsync(zrow, 0, 256, stream);
  hipLaunchKernelGGL(conv3_strip, dim3(B_ * C_), dim3(256), 0, stream,
                     x, conv_w, conv_b, zrow, feats);
  hipLaunchKernelGGL(conv1_fused, dim3(B_ * HW_ / 256), dim3(256), 0, stream,
                     feats, box_w, box_b, obj_w, obj_b, tbox, scores);
  hipLaunchKernelGGL(radix_select, dim3(B_), dim3(1024), 0, stream,
                     scores, Kout, needEq, cnt, eqCnt);
  hipLaunchKernelGGL(compact_sel, dim3(B_ * 144), dim3(256), 0, stream,
                     scores, Kout, cnt, sel, eqCnt, eqList);
  hipLaunchKernelGGL(fix_eq, dim3(B_), dim3(256), 0, stream,
                     cnt, needEq, eqCnt, eqList, sel);
  hipLaunchKernelGGL(order_decode, dim3(B_), dim3(1024), 0, stream,
                     scores, sel, tbox, s2, b2);
  hipLaunchKernelGGL(mask_kernel, dim3(B_ * 63), dim3(256), 0, stream, b2, sup);
  hipLaunchKernelGGL(nms_out, dim3(B_), dim3(64), 0, stream, sup, b2, s2, out);
}